// Round 3
// baseline (285.099 us; speedup 1.0000x reference)
//
#include <hip/hip_runtime.h>

#define K_DIM 8192
#define M_REAL 2000
#define N_REAL 2000
#define M_PAD 2048
#define N_PAD 2048

#define BM 256
#define BN 256
#define BK 32
#define SPLITK 4
#define KSLAB (K_DIM / SPLITK)   // 2048
#define NSTEP (KSLAB / BK)       // 64 K-steps per block

typedef __bf16 bf16x8 __attribute__((ext_vector_type(8)));
typedef __bf16 bf16x4 __attribute__((ext_vector_type(4)));
typedef float f32x4 __attribute__((ext_vector_type(4)));
typedef float fvec4 __attribute__((ext_vector_type(4)));

#define RAW_BARRIER()  asm volatile("s_barrier" ::: "memory")
#define LGKM0()        asm volatile("s_waitcnt lgkmcnt(0)" ::: "memory")

__device__ __forceinline__ __bf16 tobf(float f) { return (__bf16)f; }

// ---------------------------------------------------------------------------
// prep_init: out[m][n] = bias[n] for m<2000 (float4 stores, grid-stride).
// The ONLY remaining prep: f32->bf16 conversion of W and the X transpose are
// fused into the GEMM staging (reg-staged global->cvt->ds_write).
__global__ __launch_bounds__(256) void prep_init(const float* __restrict__ bias,
                                                 float* __restrict__ out) {
    const int total = M_REAL * (N_REAL / 4);   // 1,000,000 float4
    for (int i = blockIdx.x * 256 + threadIdx.x; i < total; i += 1024 * 256) {
        int m = i / (N_REAL / 4);
        int n4 = i - m * (N_REAL / 4);
        float4 bv = *(const float4*)(bias + (n4 << 2));
        *(float4*)(out + m * N_REAL + (n4 << 2)) = bv;
    }
}

// ---------------------------------------------------------------------------
// Fused-conversion split-K GEMM. 256x256 tile, BK=32, 512 thr (8 waves,
// wave-tile 128x64 = 8x4 frags of 16x16x32).
//
// Staging (replaces prep_w/prep_x + global_load_lds):
//   A: thread t -> row m=t>>1 of W (f32, k-contiguous), 16 consecutive k
//      (4x dwordx4) -> cvt -> 2x ds_write_b128 into As[m][k] bf16 (64B rows,
//      16B-chunk XOR swizzle  chunk^=(m&3), matching the reader).
//   B: thread t -> 4k x 4n block of X (natural [k][n], 4x dwordx4; X row
//      pitch 8000B === 0 mod 16 so 16B loads are aligned), register
//      transpose -> 4x ds_write_b64 into Bs[n][k] bf16 (same swizzle).
// Pipeline: loads for step s+2 issued at step s into regs (T14 async-split:
// a full step in flight, NO vmcnt wait at the barrier); cvt+ds_write for
// step s+1 done at step s into buf[nxt]; 2-deep LDS (64 KiB); ONE
// lgkmcnt(0)+s_barrier per step (cross-wave publish). All staging is plain
// C++ loads/stores -> compiler scoreboards every intra-wave dependency.
//
// Race-freedom: reads of buf[cur] and writes of buf[nxt] both complete
// before the step-s barrier (LGKM0); buf[cur] is next written at step s+1
// (after that barrier); buf[nxt] was last read at step s-1 (before the
// step-(s-1) barrier, which we passed before writing).
__global__ __launch_bounds__(512, 2) void gemm_kernel(const float* __restrict__ W,
                                                      const float* __restrict__ X,
                                                      float* __restrict__ out) {
    __shared__ __align__(16) char sm[65536];   // A: [2][16K] @0, B: [2][16K] @32768

    int f = blockIdx.x;
    int xcd = f & 7;
    int local = f >> 3;                    // 0..31
    int bz = local & 3;
    int bx = (xcd & 3) * 2 + ((local >> 2) & 1);   // 0..7
    int by = (xcd >> 2) * 4 + (local >> 3);        // 0..7

    int t = threadIdx.x;
    int w = t >> 6;              // 0..7
    int l = t & 63;
    int wm = (w >> 2) * 128;     // 0 or 128
    int wn = (w & 3) * 64;       // 0,64,128,192
    int lane16 = l & 15;
    int quad = l >> 4;
    int m0 = by * BM;
    int n0 = bx * BN;
    int ks = bz * KSLAB;

    f32x4 acc[8][4] = {};

    // ---- staging thread mapping (constants per thread) ----
    // A side: row mA, k-half khA (0 or 16 elements)
    int mA   = t >> 1;
    int khA  = (t & 1) * 16;
    int rowA = m0 + mA;
    bool aValid = (rowA < M_REAL);
    int rowAc = aValid ? rowA : 0;
    int a_c0 = (((t & 1) * 2) ^ (mA & 3)) << 4;    // phys byte of first chunk
    char* daBase = sm + mA * 64;

    // B side: k-group kg (4 rows of X), n-quad nb
    int kg  = t >> 6;                 // 0..7
    int nb  = (t & 63) * 4;           // 0..252
    int nB  = n0 + nb;
    bool bValid = (nB < N_REAL);      // nb mult of 4 -> covers nB..nB+3
    int nBc = bValid ? nB : 0;
    int cB  = kg >> 1;
    int h8  = (kg & 1) * 8;
    int b_o0 = ((cB ^ 0) << 4) + h8;
    int b_o1 = ((cB ^ 1) << 4) + h8;
    int b_o2 = ((cB ^ 2) << 4) + h8;
    int b_o3 = ((cB ^ 3) << 4) + h8;
    char* dbBase = sm + 32768 + nb * 64;
    long long kgOff = (long long)(kg * 4) * N_REAL;

    fvec4 wa0, wa1, wa2, wa3, xb0, xb1, xb2, xb3;
    const fvec4 z4 = {0.f, 0.f, 0.f, 0.f};

#define LOADG(KB) do { \
        const float* pa = W + (long long)rowAc * K_DIM + (KB) + khA; \
        wa0 = *(const fvec4*)(pa); \
        wa1 = *(const fvec4*)(pa + 4); \
        wa2 = *(const fvec4*)(pa + 8); \
        wa3 = *(const fvec4*)(pa + 12); \
        if (!aValid) { wa0 = z4; wa1 = z4; wa2 = z4; wa3 = z4; } \
        const float* pb = X + (long long)(KB) * N_REAL + kgOff + nBc; \
        xb0 = *(const fvec4*)(pb); \
        xb1 = *(const fvec4*)(pb + N_REAL); \
        xb2 = *(const fvec4*)(pb + 2 * N_REAL); \
        xb3 = *(const fvec4*)(pb + 3 * N_REAL); \
        if (!bValid) { xb0 = z4; xb1 = z4; xb2 = z4; xb3 = z4; } \
    } while (0)

#define WRITET(BUFO) do { \
        bf16x8 h0, h1; \
        h0[0] = tobf(wa0[0]); h0[1] = tobf(wa0[1]); h0[2] = tobf(wa0[2]); h0[3] = tobf(wa0[3]); \
        h0[4] = tobf(wa1[0]); h0[5] = tobf(wa1[1]); h0[6] = tobf(wa1[2]); h0[7] = tobf(wa1[3]); \
        h1[0] = tobf(wa2[0]); h1[1] = tobf(wa2[1]); h1[2] = tobf(wa2[2]); h1[3] = tobf(wa2[3]); \
        h1[4] = tobf(wa3[0]); h1[5] = tobf(wa3[1]); h1[6] = tobf(wa3[2]); h1[7] = tobf(wa3[3]); \
        *(bf16x8*)(daBase + (BUFO) + a_c0) = h0; \
        *(bf16x8*)(daBase + (BUFO) + (a_c0 ^ 16)) = h1; \
        bf16x4 v0, v1, v2, v3; \
        v0[0] = tobf(xb0[0]); v0[1] = tobf(xb1[0]); v0[2] = tobf(xb2[0]); v0[3] = tobf(xb3[0]); \
        v1[0] = tobf(xb0[1]); v1[1] = tobf(xb1[1]); v1[2] = tobf(xb2[1]); v1[3] = tobf(xb3[1]); \
        v2[0] = tobf(xb0[2]); v2[1] = tobf(xb1[2]); v2[2] = tobf(xb2[2]); v2[3] = tobf(xb3[2]); \
        v3[0] = tobf(xb0[3]); v3[1] = tobf(xb1[3]); v3[2] = tobf(xb2[3]); v3[3] = tobf(xb3[3]); \
        *(bf16x4*)(dbBase + (BUFO) + b_o0) = v0; \
        *(bf16x4*)(dbBase + (BUFO) + 64 + b_o1) = v1; \
        *(bf16x4*)(dbBase + (BUFO) + 128 + b_o2) = v2; \
        *(bf16x4*)(dbBase + (BUFO) + 192 + b_o3) = v3; \
    } while (0)

    // ---- reader-side swizzled row offsets (bytes within one 16 KB buffer) ----
    int swz = ((quad ^ (lane16 & 3)) << 4);
    int arow = (wm + lane16) * 64 + swz;
    int brow = (wn + lane16) * 64 + swz;

    // ---- prologue: step 0 tile into buf0; issue loads for step 1 ----
    LOADG(ks);
    WRITET(0);                 // compiler inserts the vmcnt wait before cvt
    LOADG(ks + BK);
    LGKM0();
    RAW_BARRIER();

    bf16x8 a0, a1, a2, a3, b0, b1, b2, b3;

    for (int s = 0; s < NSTEP; ++s) {
        int curo = (s & 1) << 14;          // 0 / 16384
        const char* Ab = sm + curo + arow;
        const char* Bb = sm + 32768 + curo + brow;
        a0 = *(const bf16x8*)(Ab);
        a1 = *(const bf16x8*)(Ab + 1024);
        a2 = *(const bf16x8*)(Ab + 2048);
        a3 = *(const bf16x8*)(Ab + 3072);
        b0 = *(const bf16x8*)(Bb);
        b1 = *(const bf16x8*)(Bb + 1024);
        b2 = *(const bf16x8*)(Bb + 2048);
        b3 = *(const bf16x8*)(Bb + 3072);

        if (s + 1 < NSTEP) {
            WRITET(curo ^ 16384);          // tile for step s+1 (regs from s-1)
            if (s + 2 < NSTEP)
                LOADG(ks + (s + 2) * BK);  // in flight across the whole step
        }

        __builtin_amdgcn_s_setprio(1);
        acc[0][0] = __builtin_amdgcn_mfma_f32_16x16x32_bf16(a0, b0, acc[0][0], 0, 0, 0);
        acc[0][1] = __builtin_amdgcn_mfma_f32_16x16x32_bf16(a0, b1, acc[0][1], 0, 0, 0);
        acc[0][2] = __builtin_amdgcn_mfma_f32_16x16x32_bf16(a0, b2, acc[0][2], 0, 0, 0);
        acc[0][3] = __builtin_amdgcn_mfma_f32_16x16x32_bf16(a0, b3, acc[0][3], 0, 0, 0);
        acc[1][0] = __builtin_amdgcn_mfma_f32_16x16x32_bf16(a1, b0, acc[1][0], 0, 0, 0);
        acc[1][1] = __builtin_amdgcn_mfma_f32_16x16x32_bf16(a1, b1, acc[1][1], 0, 0, 0);
        acc[1][2] = __builtin_amdgcn_mfma_f32_16x16x32_bf16(a1, b2, acc[1][2], 0, 0, 0);
        acc[1][3] = __builtin_amdgcn_mfma_f32_16x16x32_bf16(a1, b3, acc[1][3], 0, 0, 0);
        acc[2][0] = __builtin_amdgcn_mfma_f32_16x16x32_bf16(a2, b0, acc[2][0], 0, 0, 0);
        acc[2][1] = __builtin_amdgcn_mfma_f32_16x16x32_bf16(a2, b1, acc[2][1], 0, 0, 0);
        acc[2][2] = __builtin_amdgcn_mfma_f32_16x16x32_bf16(a2, b2, acc[2][2], 0, 0, 0);
        acc[2][3] = __builtin_amdgcn_mfma_f32_16x16x32_bf16(a2, b3, acc[2][3], 0, 0, 0);
        acc[3][0] = __builtin_amdgcn_mfma_f32_16x16x32_bf16(a3, b0, acc[3][0], 0, 0, 0);
        acc[3][1] = __builtin_amdgcn_mfma_f32_16x16x32_bf16(a3, b1, acc[3][1], 0, 0, 0);
        acc[3][2] = __builtin_amdgcn_mfma_f32_16x16x32_bf16(a3, b2, acc[3][2], 0, 0, 0);
        acc[3][3] = __builtin_amdgcn_mfma_f32_16x16x32_bf16(a3, b3, acc[3][3], 0, 0, 0);
        __builtin_amdgcn_s_setprio(0);

        // second half of the A frags (reuse regs; cur stays valid until the
        // *next* step's writes, which are after the barrier below)
        a0 = *(const bf16x8*)(Ab + 4096);
        a1 = *(const bf16x8*)(Ab + 5120);
        a2 = *(const bf16x8*)(Ab + 6144);
        a3 = *(const bf16x8*)(Ab + 7168);

        LGKM0();
        RAW_BARRIER();

        __builtin_amdgcn_s_setprio(1);
        acc[4][0] = __builtin_amdgcn_mfma_f32_16x16x32_bf16(a0, b0, acc[4][0], 0, 0, 0);
        acc[4][1] = __builtin_amdgcn_mfma_f32_16x16x32_bf16(a0, b1, acc[4][1], 0, 0, 0);
        acc[4][2] = __builtin_amdgcn_mfma_f32_16x16x32_bf16(a0, b2, acc[4][2], 0, 0, 0);
        acc[4][3] = __builtin_amdgcn_mfma_f32_16x16x32_bf16(a0, b3, acc[4][3], 0, 0, 0);
        acc[5][0] = __builtin_amdgcn_mfma_f32_16x16x32_bf16(a1, b0, acc[5][0], 0, 0, 0);
        acc[5][1] = __builtin_amdgcn_mfma_f32_16x16x32_bf16(a1, b1, acc[5][1], 0, 0, 0);
        acc[5][2] = __builtin_amdgcn_mfma_f32_16x16x32_bf16(a1, b2, acc[5][2], 0, 0, 0);
        acc[5][3] = __builtin_amdgcn_mfma_f32_16x16x32_bf16(a1, b3, acc[5][3], 0, 0, 0);
        acc[6][0] = __builtin_amdgcn_mfma_f32_16x16x32_bf16(a2, b0, acc[6][0], 0, 0, 0);
        acc[6][1] = __builtin_amdgcn_mfma_f32_16x16x32_bf16(a2, b1, acc[6][1], 0, 0, 0);
        acc[6][2] = __builtin_amdgcn_mfma_f32_16x16x32_bf16(a2, b2, acc[6][2], 0, 0, 0);
        acc[6][3] = __builtin_amdgcn_mfma_f32_16x16x32_bf16(a2, b3, acc[6][3], 0, 0, 0);
        acc[7][0] = __builtin_amdgcn_mfma_f32_16x16x32_bf16(a3, b0, acc[7][0], 0, 0, 0);
        acc[7][1] = __builtin_amdgcn_mfma_f32_16x16x32_bf16(a3, b1, acc[7][1], 0, 0, 0);
        acc[7][2] = __builtin_amdgcn_mfma_f32_16x16x32_bf16(a3, b2, acc[7][2], 0, 0, 0);
        acc[7][3] = __builtin_amdgcn_mfma_f32_16x16x32_bf16(a3, b3, acc[7][3], 0, 0, 0);
        __builtin_amdgcn_s_setprio(0);
    }
#undef LOADG
#undef WRITET

    // Epilogue: C/D layout col = lane&15, row = quad*4 + reg  [m89-verified]
#pragma unroll
    for (int j = 0; j < 4; ++j) {
        int n = n0 + wn + j * 16 + lane16;
        if (n >= N_REAL) continue;
#pragma unroll
        for (int i = 0; i < 8; ++i) {
            int mbase = m0 + wm + i * 16 + quad * 4;
#pragma unroll
            for (int r = 0; r < 4; ++r) {
                int m = mbase + r;
                if (m < M_REAL)
                    atomicAdd(&out[(long long)m * N_REAL + n], acc[i][j][r]);
            }
        }
    }
}

// ---------------------------------------------------------------------------
extern "C" void kernel_launch(void* const* d_in, const int* in_sizes, int n_in,
                              void* d_out, int out_size, void* d_ws, size_t ws_size,
                              hipStream_t stream) {
    const float* W    = (const float*)d_in[0];  // [2000][8192]
    const float* bias = (const float*)d_in[1];  // [2000]
    const float* X    = (const float*)d_in[2];  // [8192][2000]
    float* out = (float*)d_out;
    (void)d_ws; (void)ws_size;

    prep_init<<<1024, 256, 0, stream>>>(bias, out);
    gemm_kernel<<<(N_PAD / BN) * (M_PAD / BM) * SPLITK, 512, 0, stream>>>(W, X, out);
}

// Round 4
// 256.390 us; speedup vs baseline: 1.1120x; 1.1120x over previous
//
#include <hip/hip_runtime.h>

#define K_DIM 8192
#define M_REAL 2000
#define N_REAL 2000
#define M_PAD 2048
#define N_PAD 2048

#define BM 256
#define BN 256
#define BK 32
#define SPLITK 4
#define KSLAB (K_DIM / SPLITK)   // 2048
#define NSTEP (KSLAB / BK)       // 64 K-steps per block

// fused prep block ranges
#define NB_W 1024
#define NB_X 2048
#define NB_I 256

typedef __bf16 bf16x8 __attribute__((ext_vector_type(8)));
typedef float f32x4 __attribute__((ext_vector_type(4)));
typedef float fvec4 __attribute__((ext_vector_type(4)));

#define RAW_BARRIER()  asm volatile("s_barrier" ::: "memory")
#define LGKM0()        asm volatile("s_waitcnt lgkmcnt(0)" ::: "memory")
#define WAIT_VM8()     asm volatile("s_waitcnt vmcnt(8)" ::: "memory")
#define WAIT_VM4()     asm volatile("s_waitcnt vmcnt(4)" ::: "memory")
#define WAIT_VM0()     asm volatile("s_waitcnt vmcnt(0)" ::: "memory")

__device__ __forceinline__ unsigned short f2bf(float f) {
    union { float f; unsigned u; } v; v.f = f;
    unsigned r = v.u + 0x7FFFu + ((v.u >> 16) & 1u);  // RNE; inputs are finite normals
    return (unsigned short)(r >> 16);
}

__device__ __forceinline__ unsigned pk2(float a, float b) {
    return (unsigned)f2bf(a) | ((unsigned)f2bf(b) << 16);
}

__device__ __forceinline__ void async16(const void* g, void* l) {
    __builtin_amdgcn_global_load_lds((__attribute__((address_space(1))) void*)(g),
                                     (__attribute__((address_space(3))) void*)(l),
                                     16, 0, 0);
}

// ---------------------------------------------------------------------------
// Fused prep (one dispatch):
//   blocks [0,1024):       W f32 -> Wb bf16 [2048][8192], grid-stride, 32B ld/16B st
//   blocks [1024,3072):    X [8192][2000] f32 -> XT bf16 [2048][8192] transpose,
//                          conflict-free LDS (row stride 65 words === 1 mod 32)
//   blocks [3072,3328):    out[m][n] = bias[n] (float4 stores, grid-stride)
__global__ __launch_bounds__(256) void prep_kernel(const float* __restrict__ W,
                                                   const float* __restrict__ X,
                                                   const float* __restrict__ bias,
                                                   unsigned short* __restrict__ Wb,
                                                   unsigned short* __restrict__ XT,
                                                   float* __restrict__ out) {
    __shared__ unsigned short T[64][130];
    int bid = blockIdx.x;
    if (bid < NB_W) {
        unsigned tid = bid * 256u + threadIdx.x;
#pragma unroll
        for (unsigned i = 0; i < 8; ++i) {
            unsigned e = (i * (1024u * 256u) + tid) * 8u;       // element index
            uint4 o = make_uint4(0u, 0u, 0u, 0u);
            if (e < (unsigned)(M_REAL * K_DIM)) {
                fvec4 f0 = __builtin_nontemporal_load((const fvec4*)(W + e));
                fvec4 f1 = __builtin_nontemporal_load((const fvec4*)(W + e + 4));
                o.x = pk2(f0.x, f0.y);
                o.y = pk2(f0.z, f0.w);
                o.z = pk2(f1.x, f1.y);
                o.w = pk2(f1.z, f1.w);
            }
            *(uint4*)(Wb + e) = o;
        }
    } else if (bid < NB_W + NB_X) {
        int b = bid - NB_W;
        int k0 = (b & 63) << 7;        // 0..8064 step 128
        int n0 = (b >> 6) << 6;        // 0..1984 step 64
        int t = threadIdx.x;
        int c = t & 15;
        int r = t >> 4;
        int nl = c << 2;               // local n base (x4)
        int n = n0 + nl;
        bool valid = (n < N_REAL);
#pragma unroll
        for (int p = 0; p < 4; ++p) {
            int kl = (r << 1) + (p << 5);
            fvec4 v0 = {0.f, 0.f, 0.f, 0.f};
            fvec4 v1 = {0.f, 0.f, 0.f, 0.f};
            if (valid) {
                v0 = __builtin_nontemporal_load((const fvec4*)(X + (k0 + kl) * N_REAL + n));
                v1 = __builtin_nontemporal_load((const fvec4*)(X + (k0 + kl + 1) * N_REAL + n));
            }
            *(unsigned*)&T[nl + 0][kl] = pk2(v0.x, v1.x);
            *(unsigned*)&T[nl + 1][kl] = pk2(v0.y, v1.y);
            *(unsigned*)&T[nl + 2][kl] = pk2(v0.z, v1.z);
            *(unsigned*)&T[nl + 3][kl] = pk2(v0.w, v1.w);
        }
        __syncthreads();
#pragma unroll
        for (int it = 0; it < 4; ++it) {
            int nl2 = r + (it << 4);
            int kl2 = c << 3;
            const unsigned* tp = (const unsigned*)&T[nl2][kl2];
            uint4 o;
            o.x = tp[0]; o.y = tp[1]; o.z = tp[2]; o.w = tp[3];
            *(uint4*)(XT + (((n0 + nl2) << 13) + k0 + kl2)) = o;
        }
    } else {
        const int total = M_REAL * (N_REAL / 4);   // 1,000,000 float4
        for (int i = (bid - NB_W - NB_X) * 256 + (int)threadIdx.x; i < total; i += NB_I * 256) {
            int m = i / (N_REAL / 4);
            int n4 = i - m * (N_REAL / 4);
            float4 bv = *(const float4*)(bias + (n4 << 2));
            *(float4*)(out + m * N_REAL + (n4 << 2)) = bv;
        }
    }
}

// ---------------------------------------------------------------------------
// Split-K GEMM, 256x256 tile, BK=32, 4-deep LDS pipeline (128 KiB), phase-
// interleaved schedule (T3+T4): per K-step two phases, each
//   { ds_read frags | 2x global_load_lds (step s+3) | barrier | lgkmcnt(0) |
//     setprio(1) 16x MFMA setprio(0) | barrier }
// Counted vmcnt(8) once per K-step (never 0 in main loop); tail peels 4->0.
//
// T2 swizzle FIX (this round's single change vs R2): chunk ^= (row>>1)&3
// instead of chunk ^= row&3. Bank arithmetic: bank-slot = (row&1, chunk).
// Old: chunk = q^(row&3) has bit0 == row&1 -> only 4 distinct slots per 16
// lanes = 4-way conflict (1.58x, m136) on EVERY ds_read_b128. New:
// (row&1, q^((row>>1)&3)) is a bijection over each 8-row group -> 8 slots,
// 2 rows/slot = 2-way = free. Applied BOTH sides (rule #21): pre-swizzled
// global source of global_load_lds + same XOR on the reader address.
//
// Race-freedom: buffer written at step s is (s+3)&3 == (s-1)&3, last read at
// step s-1; every wave's reads completed before s-1's final barrier
// (lgkmcnt(0) precedes MFMA precedes barrier), and stores issue after it.
// vmcnt(8): the 8 newest loads are exactly steps s+2,s+3 -> step s+1 landed.
__global__ __launch_bounds__(512, 2) void gemm_kernel(const unsigned short* __restrict__ Wb,
                                                      const unsigned short* __restrict__ XT,
                                                      float* __restrict__ out) {
    __shared__ __align__(16) unsigned short As[4][BM * BK];  // 4 x 16 KB
    __shared__ __align__(16) unsigned short Bs[4][BN * BK];  // 4 x 16 KB

    int f = blockIdx.x;
    int xcd = f & 7;
    int local = f >> 3;                    // 0..31
    int bz = local & 3;
    int bx = (xcd & 3) * 2 + ((local >> 2) & 1);   // 0..7
    int by = (xcd >> 2) * 4 + (local >> 3);        // 0..7

    int t = threadIdx.x;
    int w = t >> 6;              // 0..7
    int l = t & 63;
    int wm = (w >> 2) * 128;     // 0 or 128
    int wn = (w & 3) * 64;       // 0,64,128,192
    int lane16 = l & 15;
    int quad = l >> 4;
    int m0 = by * BM;
    int n0 = bx * BN;
    int ks = bz * KSLAB;

    f32x4 acc[8][4] = {};

    // ---- staging source pointers (pre-swizzled chunk within each 64B row) ----
    int rlin = t >> 2;                       // 0..127 (round-0 row; round1 = +128)
    int ck = (t & 3) ^ ((rlin >> 1) & 3);    // 16B chunk index, swizzled (T2 fix)
    const unsigned short* gA0 = Wb + (long long)(m0 + rlin) * K_DIM + ks + ck * 8;
    const unsigned short* gA1 = gA0 + 128LL * K_DIM;
    const unsigned short* gB0 = XT + (long long)(n0 + rlin) * K_DIM + ks + ck * 8;
    const unsigned short* gB1 = gB0 + 128LL * K_DIM;

    char* smA = (char*)&As[0][0];
    char* smB = (char*)&Bs[0][0];
    int wslot = w * 1024;                    // wave-uniform LDS slot within a round

#define STAGE_A(OFF) do { \
        async16(gA0, smA + (OFF) + wslot); \
        async16(gA1, smA + (OFF) + 8192 + wslot); \
        gA0 += BK; gA1 += BK; } while (0)
#define STAGE_B(OFF) do { \
        async16(gB0, smB + (OFF) + wslot); \
        async16(gB1, smB + (OFF) + 8192 + wslot); \
        gB0 += BK; gB1 += BK; } while (0)

    // ---- reader-side swizzled row offsets (bytes within one 16 KB buffer) ----
    // row mod 8 == lane16 mod 8 for every frag (frag strides are 16 rows),
    // so (row>>1)&3 == (lane16>>1)&3.
    int swz = ((quad ^ ((lane16 >> 1) & 3)) << 4);   // 16B chunk swizzle (T2 fix)
    int arow = (wm + lane16) * 64 + swz;
    int brow = (wn + lane16) * 64 + swz;

    // ---- prologue: stage K-steps 0,1,2 (12 loads), wait for step 0 ----
    STAGE_A(0);     STAGE_B(0);
    STAGE_A(16384); STAGE_B(16384);
    STAGE_A(32768); STAGE_B(32768);
    WAIT_VM8();                      // 8 newest = steps 1,2 -> step 0 landed
    RAW_BARRIER();

    int cur = 0;
    int stg = 49152;

    bf16x8 a0, a1, a2, a3, b0, b1, b2, b3;

    for (int s = 0; s < NSTEP; ++s) {
        // ---------------- phase 1: i0-3 x j0-3 ----------------
        {
            const char* ab = smA + cur + arow;
            const char* bb = smB + cur + brow;
            a0 = *(const bf16x8*)(ab);
            a1 = *(const bf16x8*)(ab + 1024);
            a2 = *(const bf16x8*)(ab + 2048);
            a3 = *(const bf16x8*)(ab + 3072);
            b0 = *(const bf16x8*)(bb);
            b1 = *(const bf16x8*)(bb + 1024);
            b2 = *(const bf16x8*)(bb + 2048);
            b3 = *(const bf16x8*)(bb + 3072);
            if (s < NSTEP - 3) STAGE_A(stg);
            RAW_BARRIER();
            LGKM0();
            __builtin_amdgcn_s_setprio(1);
            acc[0][0] = __builtin_amdgcn_mfma_f32_16x16x32_bf16(a0, b0, acc[0][0], 0, 0, 0);
            acc[0][1] = __builtin_amdgcn_mfma_f32_16x16x32_bf16(a0, b1, acc[0][1], 0, 0, 0);
            acc[0][2] = __builtin_amdgcn_mfma_f32_16x16x32_bf16(a0, b2, acc[0][2], 0, 0, 0);
            acc[0][3] = __builtin_amdgcn_mfma_f32_16x16x32_bf16(a0, b3, acc[0][3], 0, 0, 0);
            acc[1][0] = __builtin_amdgcn_mfma_f32_16x16x32_bf16(a1, b0, acc[1][0], 0, 0, 0);
            acc[1][1] = __builtin_amdgcn_mfma_f32_16x16x32_bf16(a1, b1, acc[1][1], 0, 0, 0);
            acc[1][2] = __builtin_amdgcn_mfma_f32_16x16x32_bf16(a1, b2, acc[1][2], 0, 0, 0);
            acc[1][3] = __builtin_amdgcn_mfma_f32_16x16x32_bf16(a1, b3, acc[1][3], 0, 0, 0);
            acc[2][0] = __builtin_amdgcn_mfma_f32_16x16x32_bf16(a2, b0, acc[2][0], 0, 0, 0);
            acc[2][1] = __builtin_amdgcn_mfma_f32_16x16x32_bf16(a2, b1, acc[2][1], 0, 0, 0);
            acc[2][2] = __builtin_amdgcn_mfma_f32_16x16x32_bf16(a2, b2, acc[2][2], 0, 0, 0);
            acc[2][3] = __builtin_amdgcn_mfma_f32_16x16x32_bf16(a2, b3, acc[2][3], 0, 0, 0);
            acc[3][0] = __builtin_amdgcn_mfma_f32_16x16x32_bf16(a3, b0, acc[3][0], 0, 0, 0);
            acc[3][1] = __builtin_amdgcn_mfma_f32_16x16x32_bf16(a3, b1, acc[3][1], 0, 0, 0);
            acc[3][2] = __builtin_amdgcn_mfma_f32_16x16x32_bf16(a3, b2, acc[3][2], 0, 0, 0);
            acc[3][3] = __builtin_amdgcn_mfma_f32_16x16x32_bf16(a3, b3, acc[3][3], 0, 0, 0);
            __builtin_amdgcn_s_setprio(0);
            RAW_BARRIER();
        }
        // ---------------- phase 2: i4-7 x j0-3 ----------------
        {
            const char* ab = smA + cur + arow + 4096;
            a0 = *(const bf16x8*)(ab);
            a1 = *(const bf16x8*)(ab + 1024);
            a2 = *(const bf16x8*)(ab + 2048);
            a3 = *(const bf16x8*)(ab + 3072);
            if (s < NSTEP - 3) {
                STAGE_B(stg);
                WAIT_VM8();          // 8 newest = steps s+2,s+3 -> s+1 landed
            } else if (s == NSTEP - 3) {
                WAIT_VM4();          // 4 newest = step 63 -> step 62 landed
            } else if (s == NSTEP - 2) {
                WAIT_VM0();          // step 63 landed
            }
            RAW_BARRIER();
            LGKM0();
            __builtin_amdgcn_s_setprio(1);
            acc[4][0] = __builtin_amdgcn_mfma_f32_16x16x32_bf16(a0, b0, acc[4][0], 0, 0, 0);
            acc[4][1] = __builtin_amdgcn_mfma_f32_16x16x32_bf16(a0, b1, acc[4][1], 0, 0, 0);
            acc[4][2] = __builtin_amdgcn_mfma_f32_16x16x32_bf16(a0, b2, acc[4][2], 0, 0, 0);
            acc[4][3] = __builtin_amdgcn_mfma_f32_16x16x32_bf16(a0, b3, acc[4][3], 0, 0, 0);
            acc[5][0] = __builtin_amdgcn_mfma_f32_16x16x32_bf16(a1, b0, acc[5][0], 0, 0, 0);
            acc[5][1] = __builtin_amdgcn_mfma_f32_16x16x32_bf16(a1, b1, acc[5][1], 0, 0, 0);
            acc[5][2] = __builtin_amdgcn_mfma_f32_16x16x32_bf16(a1, b2, acc[5][2], 0, 0, 0);
            acc[5][3] = __builtin_amdgcn_mfma_f32_16x16x32_bf16(a1, b3, acc[5][3], 0, 0, 0);
            acc[6][0] = __builtin_amdgcn_mfma_f32_16x16x32_bf16(a2, b0, acc[6][0], 0, 0, 0);
            acc[6][1] = __builtin_amdgcn_mfma_f32_16x16x32_bf16(a2, b1, acc[6][1], 0, 0, 0);
            acc[6][2] = __builtin_amdgcn_mfma_f32_16x16x32_bf16(a2, b2, acc[6][2], 0, 0, 0);
            acc[6][3] = __builtin_amdgcn_mfma_f32_16x16x32_bf16(a2, b3, acc[6][3], 0, 0, 0);
            acc[7][0] = __builtin_amdgcn_mfma_f32_16x16x32_bf16(a3, b0, acc[7][0], 0, 0, 0);
            acc[7][1] = __builtin_amdgcn_mfma_f32_16x16x32_bf16(a3, b1, acc[7][1], 0, 0, 0);
            acc[7][2] = __builtin_amdgcn_mfma_f32_16x16x32_bf16(a3, b2, acc[7][2], 0, 0, 0);
            acc[7][3] = __builtin_amdgcn_mfma_f32_16x16x32_bf16(a3, b3, acc[7][3], 0, 0, 0);
            __builtin_amdgcn_s_setprio(0);
            RAW_BARRIER();
        }
        cur = (cur + 16384) & 65535;
        stg = (stg + 16384) & 65535;
    }
#undef STAGE_A
#undef STAGE_B

    // Epilogue: C/D layout col = lane&15, row = quad*4 + reg  [m89-verified]
#pragma unroll
    for (int j = 0; j < 4; ++j) {
        int n = n0 + wn + j * 16 + lane16;
        if (n >= N_REAL) continue;
#pragma unroll
        for (int i = 0; i < 8; ++i) {
            int mbase = m0 + wm + i * 16 + quad * 4;
#pragma unroll
            for (int r = 0; r < 4; ++r) {
                int m = mbase + r;
                if (m < M_REAL)
                    atomicAdd(&out[(long long)m * N_REAL + n], acc[i][j][r]);
            }
        }
    }
}

// ---------------------------------------------------------------------------
extern "C" void kernel_launch(void* const* d_in, const int* in_sizes, int n_in,
                              void* d_out, int out_size, void* d_ws, size_t ws_size,
                              hipStream_t stream) {
    const float* W    = (const float*)d_in[0];  // [2000][8192]
    const float* bias = (const float*)d_in[1];  // [2000]
    const float* X    = (const float*)d_in[2];  // [8192][2000]
    float* out = (float*)d_out;

    unsigned short* Wb = (unsigned short*)d_ws;                 // [2048][8192] bf16
    unsigned short* XT = Wb + (long long)M_PAD * K_DIM;         // [2048][8192] bf16

    prep_kernel<<<NB_W + NB_X + NB_I, 256, 0, stream>>>(W, X, bias, Wb, XT, out);

    gemm_kernel<<<(N_PAD / BN) * (M_PAD / BM) * SPLITK, 512, 0, stream>>>(Wb, XT, out);
}